// Round 12
// baseline (88.328 us; speedup 1.0000x reference)
//
#include <hip/hip_runtime.h>

#define B_DIM 1024
#define C_DIM 256
#define ELL   9
#define E_DIM 10
#define K1    1
#define K2    4
#define K3    20

// GEMM geometry: M = B*C rows, K = 224 (219 monomials + pad), N = 112 (4q x 28)
#define N_MONO3 165
#define N_MONO2 45
#define N_MONO  219
#define K_PAD   224
#define KT_N    7            // 224 / 32
#define NT_N    7            // 112 / 16
#define TP_ELEMS (KT_N * NT_N * 64 * 8)   // 25088 fp16, fragment-ordered B
#define MPITCH  232          // fp16 pitch of M rows (464B = 29 quads, odd -> conflict-free b128)
#define BPITCH  116          // f32 pitch of basis rows (464B = 29 quads; 64*116*4 == 64*232*2)
#define XS_P    12           // f32 pitch of xs rows
#define WT_P    56           // fp16 pitch of wt rows (112B = 7 quads, odd); l1 @0..24, l0 @28..52
#define WT_BYTES (64 * WT_P * 2)          // 7168 B per tile

typedef _Float16 half8 __attribute__((ext_vector_type(8)));
typedef float    f32x4 __attribute__((ext_vector_type(4)));

// ---------------------------------------------------------------------------
// Symmetrized coefficient T[k][n] (validated r8-r11).
// ---------------------------------------------------------------------------
__device__ float table_val(int k, int n,
    const float* U1_l0, const float* U2_l0, const float* U3_l0,
    const float* U1_l1, const float* U2_l1, const float* U3_l1)
{
    int q = n / 28, t = n % 28;
    if (t >= 25 || k >= N_MONO) return 0.f;
    if (k < N_MONO3) {
        if (t >= K3) return 0.f;
        int a=0,b=0,c=0,cnt=0;
        for (int ai=0; ai<ELL; ++ai)
            for (int bi=ai; bi<ELL; ++bi)
                for (int ci=bi; ci<ELL; ++ci) { if (cnt==k){a=ai;b=bi;c=ci;} ++cnt; }
        int P[6][3] = {{a,b,c},{a,c,b},{b,a,c},{b,c,a},{c,a,b},{c,b,a}};
        float s = 0.f;
        for (int tt=0; tt<6; ++tt) {
            bool dup=false;
            for (int u=0; u<tt; ++u)
                if (P[u][0]==P[tt][0]&&P[u][1]==P[tt][1]&&P[u][2]==P[tt][2]) {dup=true;break;}
            if (dup) continue;
            int p0=P[tt][0], p1=P[tt][1], p2=P[tt][2];
            s += (q==0) ? U3_l0[((p0*ELL+p1)*ELL+p2)*K3 + t]
                        : U3_l1[((((q-1)*ELL+p0)*ELL+p1)*ELL+p2)*K3 + t];
        }
        return s;
    } else if (k < N_MONO3 + N_MONO2) {
        if (t < K3 || t >= K3 + K2) return 0.f;
        int pidx = k - N_MONO3, kk = t - K3;
        int a=0,b=0,cnt=0;
        for (int ai=0; ai<ELL; ++ai)
            for (int bi=ai; bi<ELL; ++bi) { if (cnt==pidx){a=ai;b=bi;} ++cnt; }
        float s = 0.f;
        for (int tt=0; tt<2; ++tt) {
            if (tt==1 && a==b) break;
            int p0 = tt ? b : a, p1 = tt ? a : b;
            s += (q==0) ? U2_l0[(p0*ELL+p1)*K2 + kk]
                        : U2_l1[(((q-1)*ELL+p0)*ELL+p1)*K2 + kk];
        }
        return s;
    } else {
        if (t != K3 + K2) return 0.f;
        int i = k - (N_MONO3 + N_MONO2);
        return (q==0) ? U1_l0[i] : U1_l1[(q-1)*ELL + i];
    }
}

// ---------------------------------------------------------------------------
// Kernel A: pack T into MFMA B-fragment order (fp16).  (validated r8-r11)
// ---------------------------------------------------------------------------
__global__ void build_tables(const float* __restrict__ U1_l0,
                             const float* __restrict__ U2_l0,
                             const float* __restrict__ U3_l0,
                             const float* __restrict__ U1_l1,
                             const float* __restrict__ U2_l1,
                             const float* __restrict__ U3_l1,
                             _Float16* __restrict__ Tp)
{
    int idx = blockIdx.x * blockDim.x + threadIdx.x;
    if (idx >= TP_ELEMS) return;
    int e    = idx & 7;
    int lane = (idx >> 3) & 63;
    int tile = idx >> 9;            // 0..48
    int nt   = tile % NT_N;
    int kt   = tile / NT_N;
    int k = kt*32 + (lane >> 4)*8 + e;
    int n = nt*16 + (lane & 15);
    Tp[idx] = (_Float16)table_val(k, n, U1_l0, U2_l0, U3_l0, U1_l1, U2_l1, U3_l1);
}

// ---------------------------------------------------------------------------
// Kernel A2: precompute WtT[b][c][56] fp16 = weighted weights, row-major per
// (b,c) so the main kernel stages them with a pure linear b128 copy.
// ch 0..27 = l1 channel t=ch (t>=25 -> 0); ch 28..55 = l0 channel t=ch-28.
// 256 blocks x 4 b's: each weight float4... scalar load feeds 4 b-accums.
// ---------------------------------------------------------------------------
__global__ __launch_bounds__(256) void build_wt(
    const float* __restrict__ y,
    const float* __restrict__ w1_l0, const float* __restrict__ w2_l0, const float* __restrict__ w3_l0,
    const float* __restrict__ w1_l1, const float* __restrict__ w2_l1, const float* __restrict__ w3_l1,
    _Float16* __restrict__ WtT)
{
    const int c  = threadIdx.x;
    const int bb = blockIdx.x * 4;

    float yb[4][E_DIM];
    #pragma unroll
    for (int g = 0; g < 4; ++g)
        #pragma unroll
        for (int e = 0; e < E_DIM; ++e) yb[g][e] = y[(bb + g)*E_DIM + e];

    #pragma unroll
    for (int cg = 0; cg < 7; ++cg) {          // 7 groups of 8 channels
        float s[4][8];
        #pragma unroll
        for (int g = 0; g < 4; ++g)
            #pragma unroll
            for (int j = 0; j < 8; ++j) s[g][j] = 0.f;

        #pragma unroll
        for (int j = 0; j < 8; ++j) {
            const int ch  = cg*8 + j;             // compile-time
            const int par = (ch >= 28);           // 0 = l1, 1 = l0
            const int t   = ch - (par ? 28 : 0);
            if (t < 25) {
                const float* wp;
                int idx_scale;
                if (t < K3)           { wp = (par ? w3_l0 : w3_l1) + (size_t)t*C_DIM;        idx_scale = K3; }
                else if (t < K3+K2)   { wp = (par ? w2_l0 : w2_l1) + (size_t)(t-K3)*C_DIM;   idx_scale = K2; }
                else                  { wp = (par ? w1_l0 : w1_l1);                          idx_scale = K1; }
                #pragma unroll
                for (int e = 0; e < E_DIM; ++e) {
                    float wv = wp[(size_t)e*idx_scale*C_DIM + c];
                    #pragma unroll
                    for (int g = 0; g < 4; ++g)
                        s[g][j] = fmaf(yb[g][e], wv, s[g][j]);
                }
            }
        }
        #pragma unroll
        for (int g = 0; g < 4; ++g) {
            union { _Float16 h[8]; uint4 u4; } pk;
            #pragma unroll
            for (int j = 0; j < 8; ++j) pk.h[j] = (_Float16)s[g][j];
            *(uint4*)&WtT[((size_t)(bb + g)*C_DIM + c)*WT_P + cg*8] = pk.u4;
        }
    }
}

// ---------------------------------------------------------------------------
// Register-resident monomial emitter (validated r9-r11).
// ---------------------------------------------------------------------------
template<int CH>
__device__ __forceinline__ void build_M_chunk(const float* xv, _Float16* Mrow)
{
    constexpr int LO = CH*56, HI = LO + 56;
    union { _Float16 h[8]; uint4 u4; } pk;
    int m = 0;
#define EMIT(val)                                                       \
    do { if (m >= LO && m < HI) {                                       \
            pk.h[m & 7] = (_Float16)(val);                              \
            if ((m & 7) == 7) *(uint4*)&Mrow[m - 7] = pk.u4;            \
         } ++m; } while (0)

    #pragma unroll
    for (int a = 0; a < ELL; ++a)
        #pragma unroll
        for (int b = a; b < ELL; ++b) {
            float xab = xv[a] * xv[b];
            #pragma unroll
            for (int c = b; c < ELL; ++c) EMIT(xab * xv[c]);
        }
    #pragma unroll
    for (int a = 0; a < ELL; ++a)
        #pragma unroll
        for (int b = a; b < ELL; ++b) EMIT(xv[a] * xv[b]);
    #pragma unroll
    for (int i = 0; i < ELL; ++i) EMIT(xv[i]);
    #pragma unroll
    for (int p = 0; p < K_PAD - N_MONO; ++p) EMIT(0.f);
#undef EMIT
}

// ---------------------------------------------------------------------------
// Kernel B: 2048 blocks x 256 thr; block = 128 rows of one b (2 tiles of 64).
// Per tile: S (linear wt copy + coalesced xs) | P1 build M | P3 GEMM |
// P4 basis f32 row-major (BPITCH 116, 2-way-free scatter) | P5 epilogue
// (7 aligned b128 basis reads + wt row reads + 25 FMA).
// ---------------------------------------------------------------------------
__global__ __launch_bounds__(256, 4) void symcon_mfma(
    const float* __restrict__ x,
    const _Float16* __restrict__ WtT,
    const _Float16* __restrict__ Tp, float* __restrict__ out)
{
    const int bb  = blockIdx.x * 128;      // first bc-row of block
    const int b   = bb >> 8;
    const int cb0 = bb & 255;              // 0 or 128
    const int tid = threadIdx.x;
    const int w   = __builtin_amdgcn_readfirstlane(tid >> 6);  // wave id, SGPR
    const int ln  = tid & 63;

    __shared__ __align__(16) _Float16 Mh[64 * MPITCH];   // 29696 B (P4+ reuses as basis f32 [64][116])
    __shared__ __align__(16) float    xs[64 * XS_P];     //  3072 B
    __shared__ __align__(16) _Float16 wt[64 * WT_P];     //  7168 B

    // ---- hoist B-fragments (held across both tiles) ----
    half8 breg[KT_N][2];
    {
        const half8* Bp = (const half8*)Tp;
        #pragma unroll
        for (int kt = 0; kt < KT_N; ++kt)
            #pragma unroll
            for (int u = 0; u < 2; ++u) {
                int nt = 2*w + u;
                if (nt < NT_N) breg[kt][u] = Bp[(kt*NT_N + nt)*64 + ln];
            }
    }

    for (int it = 0; it < 2; ++it) {
        const int row0 = bb + it*64;       // first bc-row of tile
        const int cb   = cb0 + it*64;      // c base of tile

        // ---- S: linear wt copy (7168 B) + coalesced xs staging ----
        {
            const uint4* src = (const uint4*)(WtT + ((size_t)b*C_DIM + cb)*WT_P);
            uint4* dst = (uint4*)wt;
            for (int v = tid; v < WT_BYTES/16; v += 256) dst[v] = src[v];
        }
        for (int t = tid; t < 64*ELL; t += 256) {
            int r = t / ELL, i = t - r*ELL;
            xs[r*XS_P + i] = x[(size_t)row0*ELL + t];
        }
        __syncthreads();

        // ---- P1: build M from registers (x via LDS vector reads) ----
        {
            float xv[ELL];
            {
                const float4* xr = (const float4*)&xs[ln * XS_P];
                float4 a0 = xr[0], a1 = xr[1];
                xv[0]=a0.x; xv[1]=a0.y; xv[2]=a0.z; xv[3]=a0.w;
                xv[4]=a1.x; xv[5]=a1.y; xv[6]=a1.z; xv[7]=a1.w;
                xv[8]=xs[ln * XS_P + 8];
            }
            _Float16* Mrow = &Mh[ln * MPITCH];
            switch (w) {
                case 0:  build_M_chunk<0>(xv, Mrow); break;
                case 1:  build_M_chunk<1>(xv, Mrow); break;
                case 2:  build_M_chunk<2>(xv, Mrow); break;
                default: build_M_chunk<3>(xv, Mrow); break;
            }
        }
        __syncthreads();

        // ---- P3: GEMM (A from LDS, B from registers) ----
        f32x4 acc[2][4];
        #pragma unroll
        for (int u = 0; u < 2; ++u)
            #pragma unroll
            for (int rt = 0; rt < 4; ++rt) acc[u][rt] = (f32x4){0.f, 0.f, 0.f, 0.f};
        {
            const int l15 = ln & 15, lq = ln >> 4;
            #pragma unroll
            for (int kt = 0; kt < KT_N; ++kt) {
                half8 ar[4];
                #pragma unroll
                for (int rt = 0; rt < 4; ++rt)
                    ar[rt] = *(const half8*)&Mh[(rt*16 + l15)*MPITCH + kt*32 + lq*8];
                #pragma unroll
                for (int u = 0; u < 2; ++u) {
                    if (2*w + u < NT_N) {
                        #pragma unroll
                        for (int rt = 0; rt < 4; ++rt)
                            acc[u][rt] = __builtin_amdgcn_mfma_f32_16x16x32_f16(ar[rt], breg[kt][u], acc[u][rt], 0, 0, 0);
                    }
                }
            }
        }
        __syncthreads();   // all waves done reading Mh (about to overwrite)

        // ---- P4: basis f32 row-major [64][116] into Mh region ----
        {
            float* basis = (float*)Mh;
            const int l15 = ln & 15, lq = ln >> 4;
            #pragma unroll
            for (int u = 0; u < 2; ++u) {
                int nt = 2*w + u;
                if (nt < NT_N) {
                    #pragma unroll
                    for (int rt = 0; rt < 4; ++rt)
                        #pragma unroll
                        for (int j = 0; j < 4; ++j)
                            basis[(rt*16 + lq*4 + j)*BPITCH + nt*16 + l15] = acc[u][rt][j];
                }
            }
        }
        __syncthreads();

        // ---- P5: epilogue — wave = q, lane = row ----
        {
            const float* basis = (const float*)Mh;
            const float* brow  = basis + ln*BPITCH + w*28;
            const _Float16* wrow = wt + ln*WT_P + ((w == 0) ? 28 : 0);
            float o = 0.f;
            #pragma unroll
            for (int k = 0; k < K3 + K2 + K1; ++k)
                o = fmaf((float)wrow[k], brow[k], o);

            const int c = cb + ln;
            if (w == 0) out[b*C_DIM + c] = o;
            else        out[B_DIM*C_DIM + (size_t)(b*C_DIM + c)*3 + (w - 1)] = o;
        }
        __syncthreads();   // protect Mh/xs/wt before next tile
    }
}

// ---------------------------------------------------------------------------
extern "C" void kernel_launch(void* const* d_in, const int* in_sizes, int n_in,
                              void* d_out, int out_size, void* d_ws, size_t ws_size,
                              hipStream_t stream)
{
    const float* x     = (const float*)d_in[0];
    const float* y     = (const float*)d_in[1];
    const float* U1_l0 = (const float*)d_in[2];
    const float* U2_l0 = (const float*)d_in[3];
    const float* U3_l0 = (const float*)d_in[4];
    const float* U1_l1 = (const float*)d_in[5];
    const float* U2_l1 = (const float*)d_in[6];
    const float* U3_l1 = (const float*)d_in[7];
    const float* w1_l0 = (const float*)d_in[8];
    const float* w2_l0 = (const float*)d_in[9];
    const float* w3_l0 = (const float*)d_in[10];
    const float* w1_l1 = (const float*)d_in[11];
    const float* w2_l1 = (const float*)d_in[12];
    const float* w3_l1 = (const float*)d_in[13];

    _Float16* Tp   = (_Float16*)d_ws;                       // 50176 B
    _Float16* WtT  = (_Float16*)((char*)d_ws + 65536);      // 29.4 MB
    float*    outp = (float*)d_out;

    build_tables<<<(TP_ELEMS + 255)/256, 256, 0, stream>>>(
        U1_l0, U2_l0, U3_l0, U1_l1, U2_l1, U3_l1, Tp);

    build_wt<<<B_DIM/4, 256, 0, stream>>>(
        y, w1_l0, w2_l0, w3_l0, w1_l1, w2_l1, w3_l1, WtT);

    symcon_mfma<<<(B_DIM*C_DIM)/128, 256, 0, stream>>>(
        x, WtT, Tp, outp);
}

// Round 13
// 55.601 us; speedup vs baseline: 1.5886x; 1.5886x over previous
//
#include <hip/hip_runtime.h>

#define B_DIM 1024
#define C_DIM 256
#define ELL   9
#define E_DIM 10
#define K1    1
#define K2    4
#define K3    20

// GEMM geometry: M = B*C rows, K = 224 (219 monomials + pad), N = 112 (4q x 28)
#define N_MONO3 165
#define N_MONO2 45
#define N_MONO  219
#define K_PAD   224
#define KT_N    7            // 224 / 32
#define NT_N    7            // 112 / 16
#define TP_ELEMS (KT_N * NT_N * 64 * 8)   // 25088 fp16, fragment-ordered B
#define MPITCH  232          // fp16 pitch of M rows (464B = 29 quads, odd -> conflict-free b128)
#define BPITCH  116          // f32 pitch of basis rows
#define XS_P    12           // f32 pitch of xs rows
#define N_CG    7            // 7 channel groups of 8 (56 channels: l1 @0..24, l0 @28..52)

typedef _Float16 half8 __attribute__((ext_vector_type(8)));
typedef float    f32x4 __attribute__((ext_vector_type(4)));

// ---------------------------------------------------------------------------
// Symmetrized coefficient T[k][n] (validated r8-r12).
// ---------------------------------------------------------------------------
__device__ float table_val(int k, int n,
    const float* U1_l0, const float* U2_l0, const float* U3_l0,
    const float* U1_l1, const float* U2_l1, const float* U3_l1)
{
    int q = n / 28, t = n % 28;
    if (t >= 25 || k >= N_MONO) return 0.f;
    if (k < N_MONO3) {
        if (t >= K3) return 0.f;
        int a=0,b=0,c=0,cnt=0;
        for (int ai=0; ai<ELL; ++ai)
            for (int bi=ai; bi<ELL; ++bi)
                for (int ci=bi; ci<ELL; ++ci) { if (cnt==k){a=ai;b=bi;c=ci;} ++cnt; }
        int P[6][3] = {{a,b,c},{a,c,b},{b,a,c},{b,c,a},{c,a,b},{c,b,a}};
        float s = 0.f;
        for (int tt=0; tt<6; ++tt) {
            bool dup=false;
            for (int u=0; u<tt; ++u)
                if (P[u][0]==P[tt][0]&&P[u][1]==P[tt][1]&&P[u][2]==P[tt][2]) {dup=true;break;}
            if (dup) continue;
            int p0=P[tt][0], p1=P[tt][1], p2=P[tt][2];
            s += (q==0) ? U3_l0[((p0*ELL+p1)*ELL+p2)*K3 + t]
                        : U3_l1[((((q-1)*ELL+p0)*ELL+p1)*ELL+p2)*K3 + t];
        }
        return s;
    } else if (k < N_MONO3 + N_MONO2) {
        if (t < K3 || t >= K3 + K2) return 0.f;
        int pidx = k - N_MONO3, kk = t - K3;
        int a=0,b=0,cnt=0;
        for (int ai=0; ai<ELL; ++ai)
            for (int bi=ai; bi<ELL; ++bi) { if (cnt==pidx){a=ai;b=bi;} ++cnt; }
        float s = 0.f;
        for (int tt=0; tt<2; ++tt) {
            if (tt==1 && a==b) break;
            int p0 = tt ? b : a, p1 = tt ? a : b;
            s += (q==0) ? U2_l0[(p0*ELL+p1)*K2 + kk]
                        : U2_l1[(((q-1)*ELL+p0)*ELL+p1)*K2 + kk];
        }
        return s;
    } else {
        if (t != K3 + K2) return 0.f;
        int i = k - (N_MONO3 + N_MONO2);
        return (q==0) ? U1_l0[i] : U1_l1[(q-1)*ELL + i];
    }
}

// ---------------------------------------------------------------------------
// Kernel A: pack T into MFMA B-fragment order (fp16).  (validated r8-r12)
// ---------------------------------------------------------------------------
__global__ void build_tables(const float* __restrict__ U1_l0,
                             const float* __restrict__ U2_l0,
                             const float* __restrict__ U3_l0,
                             const float* __restrict__ U1_l1,
                             const float* __restrict__ U2_l1,
                             const float* __restrict__ U3_l1,
                             _Float16* __restrict__ Tp)
{
    int idx = blockIdx.x * blockDim.x + threadIdx.x;
    if (idx >= TP_ELEMS) return;
    int e    = idx & 7;
    int lane = (idx >> 3) & 63;
    int tile = idx >> 9;            // 0..48
    int nt   = tile % NT_N;
    int kt   = tile / NT_N;
    int k = kt*32 + (lane >> 4)*8 + e;
    int n = nt*16 + (lane & 15);
    Tp[idx] = (_Float16)table_val(k, n, U1_l0, U2_l0, U3_l0, U1_l1, U2_l1, U3_l1);
}

// ---------------------------------------------------------------------------
// Kernel A2 v2: WtT[b][cg][256c][8] fp16 (channel-group-major) so each (b,cg)
// write is 256 consecutive uint4 stores -> fully coalesced lines (r12's 4x
// write amplification fixed). Compute pattern unchanged (validated r12):
// thread = c, channels compile-time; 2 b's amortize weight loads.
// ch 0..24 = l1 channel t; 25..27 = 0; ch 28..52 = l0 t=ch-28; 53..55 = 0.
// ---------------------------------------------------------------------------
__global__ __launch_bounds__(256) void build_wt(
    const float* __restrict__ y,
    const float* __restrict__ w1_l0, const float* __restrict__ w2_l0, const float* __restrict__ w3_l0,
    const float* __restrict__ w1_l1, const float* __restrict__ w2_l1, const float* __restrict__ w3_l1,
    _Float16* __restrict__ WtT)
{
    const int c  = threadIdx.x;
    const int bb = blockIdx.x * 2;

    float yb[2][E_DIM];
    #pragma unroll
    for (int g = 0; g < 2; ++g)
        #pragma unroll
        for (int e = 0; e < E_DIM; ++e) yb[g][e] = y[(bb + g)*E_DIM + e];

    #pragma unroll
    for (int cg = 0; cg < N_CG; ++cg) {
        float s[2][8];
        #pragma unroll
        for (int g = 0; g < 2; ++g)
            #pragma unroll
            for (int j = 0; j < 8; ++j) s[g][j] = 0.f;

        #pragma unroll
        for (int j = 0; j < 8; ++j) {
            const int ch  = cg*8 + j;             // compile-time
            const int par = (ch >= 28);           // 0 = l1, 1 = l0
            const int t   = ch - (par ? 28 : 0);
            if (t < 25) {
                const float* wp;
                int ks;
                if (t < K3)           { wp = (par ? w3_l0 : w3_l1) + (size_t)t*C_DIM;        ks = K3; }
                else if (t < K3+K2)   { wp = (par ? w2_l0 : w2_l1) + (size_t)(t-K3)*C_DIM;   ks = K2; }
                else                  { wp = (par ? w1_l0 : w1_l1);                          ks = K1; }
                #pragma unroll
                for (int e = 0; e < E_DIM; ++e) {
                    float wv = wp[(size_t)e*ks*C_DIM + c];
                    s[0][j] = fmaf(yb[0][e], wv, s[0][j]);
                    s[1][j] = fmaf(yb[1][e], wv, s[1][j]);
                }
            }
        }
        #pragma unroll
        for (int g = 0; g < 2; ++g) {
            union { _Float16 h[8]; uint4 u4; } pk;
            #pragma unroll
            for (int j = 0; j < 8; ++j) pk.h[j] = (_Float16)s[g][j];
            *(uint4*)&WtT[((size_t)((bb + g)*N_CG + cg)*C_DIM + c)*8] = pk.u4;
        }
    }
}

// ---------------------------------------------------------------------------
// Register-resident monomial emitter (validated r9-r12).
// ---------------------------------------------------------------------------
template<int CH>
__device__ __forceinline__ void build_M_chunk(const float* xv, _Float16* Mrow)
{
    constexpr int LO = CH*56, HI = LO + 56;
    union { _Float16 h[8]; uint4 u4; } pk;
    int m = 0;
#define EMIT(val)                                                       \
    do { if (m >= LO && m < HI) {                                       \
            pk.h[m & 7] = (_Float16)(val);                              \
            if ((m & 7) == 7) *(uint4*)&Mrow[m - 7] = pk.u4;            \
         } ++m; } while (0)

    #pragma unroll
    for (int a = 0; a < ELL; ++a)
        #pragma unroll
        for (int b = a; b < ELL; ++b) {
            float xab = xv[a] * xv[b];
            #pragma unroll
            for (int c = b; c < ELL; ++c) EMIT(xab * xv[c]);
        }
    #pragma unroll
    for (int a = 0; a < ELL; ++a)
        #pragma unroll
        for (int b = a; b < ELL; ++b) EMIT(xv[a] * xv[b]);
    #pragma unroll
    for (int i = 0; i < ELL; ++i) EMIT(xv[i]);
    #pragma unroll
    for (int p = 0; p < K_PAD - N_MONO; ++p) EMIT(0.f);
#undef EMIT
}

// ---------------------------------------------------------------------------
// Kernel B: 2048 blocks x 256 thr; block = 128 rows of one b (2 tiles of 64).
// Per tile: S (linear wt copy [7][64][8] + coalesced xs) | P1 build M |
// P3 GEMM | P4 basis f32 row-major | P5 epilogue (4x conflict-free b128 wt
// reads + 7 b128 basis reads + 25 FMA).
// ---------------------------------------------------------------------------
__global__ __launch_bounds__(256, 4) void symcon_mfma(
    const float* __restrict__ x,
    const _Float16* __restrict__ WtT,
    const _Float16* __restrict__ Tp, float* __restrict__ out)
{
    const int bb  = blockIdx.x * 128;      // first bc-row of block
    const int b   = bb >> 8;
    const int cb0 = bb & 255;              // 0 or 128
    const int tid = threadIdx.x;
    const int w   = __builtin_amdgcn_readfirstlane(tid >> 6);  // wave id, SGPR
    const int ln  = tid & 63;

    __shared__ __align__(16) _Float16 Mh[64 * MPITCH];   // 29696 B (P4+ reuses as basis f32 [64][116])
    __shared__ __align__(16) float    xs[64 * XS_P];     //  3072 B
    __shared__ __align__(16) _Float16 wt[N_CG * 64 * 8]; //  7168 B, [cg][64][8]

    // ---- hoist B-fragments (held across both tiles) ----
    half8 breg[KT_N][2];
    {
        const half8* Bp = (const half8*)Tp;
        #pragma unroll
        for (int kt = 0; kt < KT_N; ++kt)
            #pragma unroll
            for (int u = 0; u < 2; ++u) {
                int nt = 2*w + u;
                if (nt < NT_N) breg[kt][u] = Bp[(kt*NT_N + nt)*64 + ln];
            }
    }

    for (int it = 0; it < 2; ++it) {
        const int row0 = bb + it*64;       // first bc-row of tile
        const int cb   = cb0 + it*64;      // c base of tile

        // ---- S: wt copy (each wave-chunk of 64 uint4 is contiguous) + xs ----
        {
            const uint4* src = (const uint4*)WtT;
            uint4* dst = (uint4*)wt;
            for (int v = tid; v < N_CG * 64; v += 256) {
                int cg = v >> 6, cc = v & 63;
                dst[v] = src[(size_t)(b*N_CG + cg)*C_DIM + cb + cc];
            }
        }
        for (int t = tid; t < 64*ELL; t += 256) {
            int r = t / ELL, i = t - r*ELL;
            xs[r*XS_P + i] = x[(size_t)row0*ELL + t];
        }
        __syncthreads();

        // ---- P1: build M from registers (x via LDS vector reads) ----
        {
            float xv[ELL];
            {
                const float4* xr = (const float4*)&xs[ln * XS_P];
                float4 a0 = xr[0], a1 = xr[1];
                xv[0]=a0.x; xv[1]=a0.y; xv[2]=a0.z; xv[3]=a0.w;
                xv[4]=a1.x; xv[5]=a1.y; xv[6]=a1.z; xv[7]=a1.w;
                xv[8]=xs[ln * XS_P + 8];
            }
            _Float16* Mrow = &Mh[ln * MPITCH];
            switch (w) {
                case 0:  build_M_chunk<0>(xv, Mrow); break;
                case 1:  build_M_chunk<1>(xv, Mrow); break;
                case 2:  build_M_chunk<2>(xv, Mrow); break;
                default: build_M_chunk<3>(xv, Mrow); break;
            }
        }
        __syncthreads();

        // ---- P3: GEMM (A from LDS, B from registers) ----
        f32x4 acc[2][4];
        #pragma unroll
        for (int u = 0; u < 2; ++u)
            #pragma unroll
            for (int rt = 0; rt < 4; ++rt) acc[u][rt] = (f32x4){0.f, 0.f, 0.f, 0.f};
        {
            const int l15 = ln & 15, lq = ln >> 4;
            #pragma unroll
            for (int kt = 0; kt < KT_N; ++kt) {
                half8 ar[4];
                #pragma unroll
                for (int rt = 0; rt < 4; ++rt)
                    ar[rt] = *(const half8*)&Mh[(rt*16 + l15)*MPITCH + kt*32 + lq*8];
                #pragma unroll
                for (int u = 0; u < 2; ++u) {
                    if (2*w + u < NT_N) {
                        #pragma unroll
                        for (int rt = 0; rt < 4; ++rt)
                            acc[u][rt] = __builtin_amdgcn_mfma_f32_16x16x32_f16(ar[rt], breg[kt][u], acc[u][rt], 0, 0, 0);
                    }
                }
            }
        }
        __syncthreads();   // all waves done reading Mh (about to overwrite)

        // ---- P4: basis f32 row-major [64][116] into Mh region ----
        {
            float* basis = (float*)Mh;
            const int l15 = ln & 15, lq = ln >> 4;
            #pragma unroll
            for (int u = 0; u < 2; ++u) {
                int nt = 2*w + u;
                if (nt < NT_N) {
                    #pragma unroll
                    for (int rt = 0; rt < 4; ++rt)
                        #pragma unroll
                        for (int j = 0; j < 4; ++j)
                            basis[(rt*16 + lq*4 + j)*BPITCH + nt*16 + l15] = acc[u][rt][j];
                }
            }
        }
        __syncthreads();

        // ---- P5: epilogue — wave = q, lane = row ----
        {
            const float* basis = (const float*)Mh;
            const float* brow  = basis + ln*BPITCH + w*28;

            // wt reads: 4 conflict-free b128 (lane-consecutive 16B)
            half8 wreg[4];
            if (w == 0) {          // l0: ch 28..52 -> cg 3..6
                #pragma unroll
                for (int i = 0; i < 4; ++i)
                    wreg[i] = *(const half8*)&wt[((3 + i)*64 + ln)*8];
            } else {               // l1: ch 0..24 -> cg 0..3
                #pragma unroll
                for (int i = 0; i < 4; ++i)
                    wreg[i] = *(const half8*)&wt[(i*64 + ln)*8];
            }

            float o = 0.f;
            if (w == 0) {
                #pragma unroll
                for (int k = 0; k < K3 + K2 + K1; ++k) {
                    const int ch = 28 + k;                    // compile-time
                    o = fmaf((float)wreg[(ch >> 3) - 3][ch & 7], brow[k], o);
                }
            } else {
                #pragma unroll
                for (int k = 0; k < K3 + K2 + K1; ++k)
                    o = fmaf((float)wreg[k >> 3][k & 7], brow[k], o);
            }

            const int c = cb + ln;
            if (w == 0) out[b*C_DIM + c] = o;
            else        out[B_DIM*C_DIM + (size_t)(b*C_DIM + c)*3 + (w - 1)] = o;
        }
        __syncthreads();   // protect Mh/xs/wt before next tile
    }
}

// ---------------------------------------------------------------------------
extern "C" void kernel_launch(void* const* d_in, const int* in_sizes, int n_in,
                              void* d_out, int out_size, void* d_ws, size_t ws_size,
                              hipStream_t stream)
{
    const float* x     = (const float*)d_in[0];
    const float* y     = (const float*)d_in[1];
    const float* U1_l0 = (const float*)d_in[2];
    const float* U2_l0 = (const float*)d_in[3];
    const float* U3_l0 = (const float*)d_in[4];
    const float* U1_l1 = (const float*)d_in[5];
    const float* U2_l1 = (const float*)d_in[6];
    const float* U3_l1 = (const float*)d_in[7];
    const float* w1_l0 = (const float*)d_in[8];
    const float* w2_l0 = (const float*)d_in[9];
    const float* w3_l0 = (const float*)d_in[10];
    const float* w1_l1 = (const float*)d_in[11];
    const float* w2_l1 = (const float*)d_in[12];
    const float* w3_l1 = (const float*)d_in[13];

    _Float16* Tp   = (_Float16*)d_ws;                       // 50176 B
    _Float16* WtT  = (_Float16*)((char*)d_ws + 65536);      // 29.36 MB
    float*    outp = (float*)d_out;

    build_tables<<<(TP_ELEMS + 255)/256, 256, 0, stream>>>(
        U1_l0, U2_l0, U3_l0, U1_l1, U2_l1, U3_l1, Tp);

    build_wt<<<B_DIM/2, 256, 0, stream>>>(
        y, w1_l0, w2_l0, w3_l0, w1_l1, w2_l1, w3_l1, WtT);

    symcon_mfma<<<(B_DIM*C_DIM)/128, 256, 0, stream>>>(
        x, WtT, Tp, outp);
}

// Round 15
// 40.406 us; speedup vs baseline: 2.1860x; 1.3761x over previous
//
#include <hip/hip_runtime.h>

#define B_DIM 1024
#define C_DIM 256
#define ELL   9
#define E_DIM 10
#define K1    1
#define K2    4
#define K3    20

// GEMM geometry: M = B*C rows, K = 224 (219 monomials + pad), N = 112 (4q x 28)
#define N_MONO3 165
#define N_MONO2 45
#define N_MONO  219
#define K_PAD   224
#define KT_N    7            // 224 / 32
#define NT_N    7            // 112 / 16
#define TP_ELEMS (KT_N * NT_N * 64 * 8)   // 25088 fp16, fragment-ordered B
#define MPITCH  232          // fp16 pitch of M rows (464B = 29 quads, odd -> conflict-free b128)
#define BPITCH  116          // f32 pitch of basis rows (reuses Mh region: 64*116*4 == 64*232*2)
#define XS_P    12           // f32 pitch of xs rows
#define WT_CH   50           // 25 l1 channels (rows 0..24) + 25 l0 (rows 25..49)

typedef _Float16 half8 __attribute__((ext_vector_type(8)));
typedef float    f32x4 __attribute__((ext_vector_type(4)));

// ---------------------------------------------------------------------------
// Symmetrized coefficient T[k][n] (validated r8-r13).
// ---------------------------------------------------------------------------
__device__ float table_val(int k, int n,
    const float* U1_l0, const float* U2_l0, const float* U3_l0,
    const float* U1_l1, const float* U2_l1, const float* U3_l1)
{
    int q = n / 28, t = n % 28;
    if (t >= 25 || k >= N_MONO) return 0.f;
    if (k < N_MONO3) {
        if (t >= K3) return 0.f;
        int a=0,b=0,c=0,cnt=0;
        for (int ai=0; ai<ELL; ++ai)
            for (int bi=ai; bi<ELL; ++bi)
                for (int ci=bi; ci<ELL; ++ci) { if (cnt==k){a=ai;b=bi;c=ci;} ++cnt; }
        int P[6][3] = {{a,b,c},{a,c,b},{b,a,c},{b,c,a},{c,a,b},{c,b,a}};
        float s = 0.f;
        for (int tt=0; tt<6; ++tt) {
            bool dup=false;
            for (int u=0; u<tt; ++u)
                if (P[u][0]==P[tt][0]&&P[u][1]==P[tt][1]&&P[u][2]==P[tt][2]) {dup=true;break;}
            if (dup) continue;
            int p0=P[tt][0], p1=P[tt][1], p2=P[tt][2];
            s += (q==0) ? U3_l0[((p0*ELL+p1)*ELL+p2)*K3 + t]
                        : U3_l1[((((q-1)*ELL+p0)*ELL+p1)*ELL+p2)*K3 + t];
        }
        return s;
    } else if (k < N_MONO3 + N_MONO2) {
        if (t < K3 || t >= K3 + K2) return 0.f;
        int pidx = k - N_MONO3, kk = t - K3;
        int a=0,b=0,cnt=0;
        for (int ai=0; ai<ELL; ++ai)
            for (int bi=ai; bi<ELL; ++bi) { if (cnt==pidx){a=ai;b=bi;} ++cnt; }
        float s = 0.f;
        for (int tt=0; tt<2; ++tt) {
            if (tt==1 && a==b) break;
            int p0 = tt ? b : a, p1 = tt ? a : b;
            s += (q==0) ? U2_l0[(p0*ELL+p1)*K2 + kk]
                        : U2_l1[(((q-1)*ELL+p0)*ELL+p1)*K2 + kk];
        }
        return s;
    } else {
        if (t != K3 + K2) return 0.f;
        int i = k - (N_MONO3 + N_MONO2);
        return (q==0) ? U1_l0[i] : U1_l1[(q-1)*ELL + i];
    }
}

// ---------------------------------------------------------------------------
// Kernel A: pack T into MFMA B-fragment order (fp16).  (validated r8-r13)
// ---------------------------------------------------------------------------
__global__ void build_tables(const float* __restrict__ U1_l0,
                             const float* __restrict__ U2_l0,
                             const float* __restrict__ U3_l0,
                             const float* __restrict__ U1_l1,
                             const float* __restrict__ U2_l1,
                             const float* __restrict__ U3_l1,
                             _Float16* __restrict__ Tp)
{
    int idx = blockIdx.x * blockDim.x + threadIdx.x;
    if (idx >= TP_ELEMS) return;
    int e    = idx & 7;
    int lane = (idx >> 3) & 63;
    int tile = idx >> 9;            // 0..48
    int nt   = tile % NT_N;
    int kt   = tile / NT_N;
    int k = kt*32 + (lane >> 4)*8 + e;
    int n = nt*16 + (lane & 15);
    Tp[idx] = (_Float16)table_val(k, n, U1_l0, U2_l0, U3_l0, U1_l1, U2_l1, U3_l1);
}

// ---------------------------------------------------------------------------
// Register-resident monomial emitter (validated r9-r13).
// ---------------------------------------------------------------------------
template<int CH>
__device__ __forceinline__ void build_M_chunk(const float* xv, _Float16* Mrow)
{
    constexpr int LO = CH*56, HI = LO + 56;
    union { _Float16 h[8]; uint4 u4; } pk;
    int m = 0;
#define EMIT(val)                                                       \
    do { if (m >= LO && m < HI) {                                       \
            pk.h[m & 7] = (_Float16)(val);                              \
            if ((m & 7) == 7) *(uint4*)&Mrow[m - 7] = pk.u4;            \
         } ++m; } while (0)

    #pragma unroll
    for (int a = 0; a < ELL; ++a)
        #pragma unroll
        for (int b = a; b < ELL; ++b) {
            float xab = xv[a] * xv[b];
            #pragma unroll
            for (int c = b; c < ELL; ++c) EMIT(xab * xv[c]);
        }
    #pragma unroll
    for (int a = 0; a < ELL; ++a)
        #pragma unroll
        for (int b = a; b < ELL; ++b) EMIT(xv[a] * xv[b]);
    #pragma unroll
    for (int i = 0; i < ELL; ++i) EMIT(xv[i]);
    #pragma unroll
    for (int p = 0; p < K_PAD - N_MONO; ++p) EMIT(0.f);
#undef EMIT
}

// ---------------------------------------------------------------------------
// Kernel B = r13's main kernel with the wt staging fused back in (r11's S).
// 2048 blocks x 256 thr; block = 128 rows of one b (2 tiles of 64).
// Every phase pairing below is taken verbatim from a PASSING round:
//   S  (r11): coalesced xs stage + in-kernel wt staging -> wt[50][64] fp16
//   P1 (r9-r13): build M in registers -> ds_write_b128
//   P3 (r12/r13): wave w owns n-tiles {2w,2w+1} x 4 row-tiles, breg hoisted
//   P4 (r12/r13): basis f32 row-major [64][116], column-ownership writes
//   P5 (r11 wt-read + r13 basis-read): 25 FMA epilogue
// LDS 38.3 KB -> 4 blocks/CU.
// ---------------------------------------------------------------------------
__global__ __launch_bounds__(256, 4) void symcon_mfma(
    const float* __restrict__ x,  const float* __restrict__ y,
    const float* __restrict__ w1_l0, const float* __restrict__ w2_l0, const float* __restrict__ w3_l0,
    const float* __restrict__ w1_l1, const float* __restrict__ w2_l1, const float* __restrict__ w3_l1,
    const _Float16* __restrict__ Tp, float* __restrict__ out)
{
    const int bb  = blockIdx.x * 128;      // first bc-row of block
    const int b   = bb >> 8;
    const int cb0 = bb & 255;              // 0 or 128
    const int tid = threadIdx.x;
    const int w   = __builtin_amdgcn_readfirstlane(tid >> 6);  // wave id, SGPR
    const int ln  = tid & 63;

    __shared__ __align__(16) _Float16 Mh[64 * MPITCH];   // 29696 B (reused as basis f32 [64][116])
    __shared__ __align__(16) float    xs[64 * XS_P];     //  3072 B
    __shared__ __align__(16) _Float16 wt[WT_CH][64];     //  6400 B

    float yb[E_DIM];
    #pragma unroll
    for (int e = 0; e < E_DIM; ++e) yb[e] = y[b*E_DIM + e];   // uniform -> s_load

    // ---- hoist B-fragments (held across both tiles; r13-validated) ----
    half8 breg[KT_N][2];
    {
        const half8* Bp = (const half8*)Tp;
        #pragma unroll
        for (int kt = 0; kt < KT_N; ++kt)
            #pragma unroll
            for (int u = 0; u < 2; ++u) {
                int nt = 2*w + u;
                if (nt < NT_N) breg[kt][u] = Bp[(kt*NT_N + nt)*64 + ln];
            }
    }

    for (int it = 0; it < 2; ++it) {
        const int row0 = bb + it*64;       // first bc-row of tile
        const int cb   = cb0 + it*64;      // c base of tile

        // ---- S: coalesced xs staging + wt staging (r11-validated) ----
        for (int t = tid; t < 64*ELL; t += 256) {
            int r = t / ELL, i = t - r*ELL;
            xs[r*XS_P + i] = x[(size_t)row0*ELL + t];
        }
        for (int v = tid; v < WT_CH * 16; v += 256) {
            int kk = v >> 4;                 // 0..49 (0..24 l1, 25..49 l0)
            int c4 = (v & 15) << 2;          // 0,4,..,60
            int t  = (kk >= 25) ? kk - 25 : kk;
            const float* wp;
            int ks;
            if (t < K3)            { wp = (kk >= 25 ? w3_l0 : w3_l1) + (size_t)t*C_DIM;        ks = K3; }
            else if (t < K3 + K2)  { wp = (kk >= 25 ? w2_l0 : w2_l1) + (size_t)(t - K3)*C_DIM; ks = K2; }
            else                   { wp = (kk >= 25 ? w1_l0 : w1_l1);                          ks = K1; }
            float s0 = 0.f, s1 = 0.f, s2 = 0.f, s3 = 0.f;
            #pragma unroll
            for (int e = 0; e < E_DIM; ++e) {
                float4 wv = *(const float4*)&wp[(size_t)e*ks*C_DIM + cb + c4];
                s0 = fmaf(yb[e], wv.x, s0);
                s1 = fmaf(yb[e], wv.y, s1);
                s2 = fmaf(yb[e], wv.z, s2);
                s3 = fmaf(yb[e], wv.w, s3);
            }
            union { _Float16 h[4]; uint2 u2; } cv;
            cv.h[0] = (_Float16)s0; cv.h[1] = (_Float16)s1;
            cv.h[2] = (_Float16)s2; cv.h[3] = (_Float16)s3;
            *(uint2*)&wt[kk][c4] = cv.u2;
        }
        __syncthreads();

        // ---- P1: build M from registers (x via LDS vector reads) ----
        {
            float xv[ELL];
            {
                const float4* xr = (const float4*)&xs[ln * XS_P];
                float4 a0 = xr[0], a1 = xr[1];
                xv[0]=a0.x; xv[1]=a0.y; xv[2]=a0.z; xv[3]=a0.w;
                xv[4]=a1.x; xv[5]=a1.y; xv[6]=a1.z; xv[7]=a1.w;
                xv[8]=xs[ln * XS_P + 8];
            }
            _Float16* Mrow = &Mh[ln * MPITCH];
            switch (w) {
                case 0:  build_M_chunk<0>(xv, Mrow); break;
                case 1:  build_M_chunk<1>(xv, Mrow); break;
                case 2:  build_M_chunk<2>(xv, Mrow); break;
                default: build_M_chunk<3>(xv, Mrow); break;
            }
        }
        __syncthreads();

        // ---- P3: GEMM, wave owns n-tiles {2w,2w+1} x 4 row-tiles (r13) ----
        f32x4 acc[2][4];
        #pragma unroll
        for (int u = 0; u < 2; ++u)
            #pragma unroll
            for (int rt = 0; rt < 4; ++rt) acc[u][rt] = (f32x4){0.f, 0.f, 0.f, 0.f};
        {
            const int l15 = ln & 15, lq = ln >> 4;
            #pragma unroll
            for (int kt = 0; kt < KT_N; ++kt) {
                half8 ar[4];
                #pragma unroll
                for (int rt = 0; rt < 4; ++rt)
                    ar[rt] = *(const half8*)&Mh[(rt*16 + l15)*MPITCH + kt*32 + lq*8];
                #pragma unroll
                for (int u = 0; u < 2; ++u) {
                    if (2*w + u < NT_N) {
                        #pragma unroll
                        for (int rt = 0; rt < 4; ++rt)
                            acc[u][rt] = __builtin_amdgcn_mfma_f32_16x16x32_f16(ar[rt], breg[kt][u], acc[u][rt], 0, 0, 0);
                    }
                }
            }
        }
        __syncthreads();   // all waves done reading Mh (about to overwrite)

        // ---- P4: basis f32 row-major [64][116] into Mh region (r13) ----
        {
            float* basis = (float*)Mh;
            const int l15 = ln & 15, lq = ln >> 4;
            #pragma unroll
            for (int u = 0; u < 2; ++u) {
                int nt = 2*w + u;
                if (nt < NT_N) {
                    #pragma unroll
                    for (int rt = 0; rt < 4; ++rt)
                        #pragma unroll
                        for (int j = 0; j < 4; ++j)
                            basis[(rt*16 + lq*4 + j)*BPITCH + nt*16 + l15] = acc[u][rt][j];
                }
            }
        }
        __syncthreads();

        // ---- P5: epilogue — wave = q, lane = row (r13 basis + r11 wt) ----
        {
            const float* basis = (const float*)Mh;
            const float* brow  = basis + ln*BPITCH + w*28;
            const int    base  = (w == 0) ? 25 : 0;       // l0 wt rows at 25..49
            float o = 0.f;
            #pragma unroll
            for (int k = 0; k < K3 + K2 + K1; ++k)
                o = fmaf((float)wt[base + k][ln], brow[k], o);

            const int c = cb + ln;
            if (w == 0) out[b*C_DIM + c] = o;
            else        out[B_DIM*C_DIM + (size_t)(b*C_DIM + c)*3 + (w - 1)] = o;
        }
        __syncthreads();   // protect Mh/xs/wt before next tile
    }
}

// ---------------------------------------------------------------------------
extern "C" void kernel_launch(void* const* d_in, const int* in_sizes, int n_in,
                              void* d_out, int out_size, void* d_ws, size_t ws_size,
                              hipStream_t stream)
{
    const float* x     = (const float*)d_in[0];
    const float* y     = (const float*)d_in[1];
    const float* U1_l0 = (const float*)d_in[2];
    const float* U2_l0 = (const float*)d_in[3];
    const float* U3_l0 = (const float*)d_in[4];
    const float* U1_l1 = (const float*)d_in[5];
    const float* U2_l1 = (const float*)d_in[6];
    const float* U3_l1 = (const float*)d_in[7];
    const float* w1_l0 = (const float*)d_in[8];
    const float* w2_l0 = (const float*)d_in[9];
    const float* w3_l0 = (const float*)d_in[10];
    const float* w1_l1 = (const float*)d_in[11];
    const float* w2_l1 = (const float*)d_in[12];
    const float* w3_l1 = (const float*)d_in[13];

    _Float16* Tp   = (_Float16*)d_ws;     // 50176 B used
    float*    outp = (float*)d_out;

    build_tables<<<(TP_ELEMS + 255)/256, 256, 0, stream>>>(
        U1_l0, U2_l0, U3_l0, U1_l1, U2_l1, U3_l1, Tp);

    symcon_mfma<<<(B_DIM*C_DIM)/128, 256, 0, stream>>>(
        x, y, w1_l0, w2_l0, w3_l0, w1_l1, w2_l1, w3_l1, Tp, outp);
}